// Round 1
// baseline (671.478 us; speedup 1.0000x reference)
//
#include <hip/hip_runtime.h>
#include <math.h>

#define BATCH   32
#define HIDDEN  1152
#define FREQ    256
#define HALF    128
#define SEQLEN  4096

// ---------------------------------------------------------------------------
// Kernel 1: sinusoidal embedding + first GEMM (256 -> 1152) + tanh-GELU.
// One block per batch element, 256 threads. emb staged in LDS (all-lane
// broadcast reads are conflict-free).
// ---------------------------------------------------------------------------
__global__ __launch_bounds__(256) void k_hidden(const float* __restrict__ t,
                                                const float* __restrict__ W1,
                                                const float* __restrict__ b1,
                                                float* __restrict__ h_out) {
    __shared__ float emb[FREQ];
    const int b   = blockIdx.x;
    const int tid = threadIdx.x;
    const float tb = t[b];

    // emb[f] = cos(t*freq[f])        for f in [0,128)
    //        = sin(t*freq[f-128])    for f in [128,256)
    {
        const int   j    = tid & (HALF - 1);
        const float freq = expf(-9.210340371976184f * (float)j * (1.0f / (float)HALF));
        const float arg  = tb * freq;
        emb[tid] = (tid < HALF) ? cosf(arg) : sinf(arg);
    }
    __syncthreads();

    // h[o] = gelu(emb . W1[o,:] + b1[o]); 1152 = 4*256 + 128 outputs/block
    for (int o = tid; o < HIDDEN; o += 256) {
        const float4* __restrict__ w4 = reinterpret_cast<const float4*>(W1 + (size_t)o * FREQ);
        float s0 = 0.f, s1 = 0.f, s2 = 0.f, s3 = 0.f;
#pragma unroll 8
        for (int k4 = 0; k4 < FREQ / 4; ++k4) {
            const float4 w = w4[k4];
            s0 += w.x * emb[4 * k4 + 0];
            s1 += w.y * emb[4 * k4 + 1];
            s2 += w.z * emb[4 * k4 + 2];
            s3 += w.w * emb[4 * k4 + 3];
        }
        const float x  = (s0 + s1) + (s2 + s3) + b1[o];
        const float x3 = x * x * x;
        const float g  = 0.5f * x * (1.0f + tanhf(0.7978845608028654f * (x + 0.044715f * x3)));
        h_out[b * HIDDEN + o] = g;
    }
}

// ---------------------------------------------------------------------------
// Kernel 2: second GEMM (1152 -> 1152). Grid (9, 32) x 128 threads; each
// thread computes one output via a 1152-long dot against LDS-staged h[b,:].
// ---------------------------------------------------------------------------
__global__ __launch_bounds__(128) void k_out(const float* __restrict__ h,
                                             const float* __restrict__ W2,
                                             const float* __restrict__ b2,
                                             float* __restrict__ outv) {
    __shared__ float hs[HIDDEN];
    const int b = blockIdx.y;
    const int o = blockIdx.x * 128 + threadIdx.x;   // 9*128 == 1152 exactly

    for (int k = threadIdx.x; k < HIDDEN; k += 128)
        hs[k] = h[b * HIDDEN + k];
    __syncthreads();

    const float4* __restrict__ w4 = reinterpret_cast<const float4*>(W2 + (size_t)o * HIDDEN);
    float s0 = 0.f, s1 = 0.f, s2 = 0.f, s3 = 0.f;
#pragma unroll 4
    for (int k4 = 0; k4 < HIDDEN / 4; ++k4) {
        const float4 w = w4[k4];
        s0 += w.x * hs[4 * k4 + 0];
        s1 += w.y * hs[4 * k4 + 1];
        s2 += w.z * hs[4 * k4 + 2];
        s3 += w.w * hs[4 * k4 + 3];
    }
    outv[b * HIDDEN + o] = (s0 + s1) + (s2 + s3) + b2[o];
}

// ---------------------------------------------------------------------------
// Kernel 3: broadcast out[b,h] across SEQLEN. 604 MB of pure f32 stores —
// the entire op's roofline. 16 B/lane coalesced float4 stores, grid-stride.
// Value read is wave-uniform (1024 float4 per row) -> L1/L2 broadcast hit.
// ---------------------------------------------------------------------------
__global__ __launch_bounds__(256) void k_bcast(const float* __restrict__ outv,
                                               float4* __restrict__ dst) {
    const int total4 = BATCH * HIDDEN * (SEQLEN / 4);   // 37,748,736
    const int stride = gridDim.x * blockDim.x;
    for (int i = blockIdx.x * blockDim.x + threadIdx.x; i < total4; i += stride) {
        const float v = outv[i >> 10];                  // 1024 float4 per (b,h) row
        const float4 val = {v, v, v, v};
        dst[i] = val;
    }
}

extern "C" void kernel_launch(void* const* d_in, const int* in_sizes, int n_in,
                              void* d_out, int out_size, void* d_ws, size_t ws_size,
                              hipStream_t stream) {
    const float* t  = (const float*)d_in[0];
    const float* W1 = (const float*)d_in[1];
    const float* b1 = (const float*)d_in[2];
    const float* W2 = (const float*)d_in[3];
    const float* b2 = (const float*)d_in[4];
    float* outf = (float*)d_out;

    float* h  = (float*)d_ws;            // 32*1152 f32 = 147,456 B
    float* ov = h + BATCH * HIDDEN;      // 32*1152 f32 = 147,456 B (total 288 KB)

    k_hidden<<<BATCH, 256, 0, stream>>>(t, W1, b1, h);
    k_out<<<dim3(HIDDEN / 128, BATCH), 128, 0, stream>>>(h, W2, b2, ov);
    k_bcast<<<2048, 256, 0, stream>>>(ov, (float4*)outf);
}